// Round 9
// baseline (2054.798 us; speedup 1.0000x reference)
//
#include <hip/hip_runtime.h>
#include <math.h>

#define Bg 32
#define Ng 2048
#define Kn 20
#define BNn (Bg*Ng)
#define En (BNn*Kn)
#define Hd 64
#define Cd 40

// knn-mfma params
#define KK 24            // approx top-K kept per j-quarter (96 cands/row)
#define CAPB 8

typedef __attribute__((ext_vector_type(8))) short bf16x8;
typedef __attribute__((ext_vector_type(4))) float f32x4;

// ---------- weight prep
__global__ void prep_w_kernel(const float* __restrict__ w1c, const float* __restrict__ w1d1,
                              const float* __restrict__ w1d2,
                              float* __restrict__ wpq0, float* __restrict__ wpq1,
                              float* __restrict__ wpq2){
  int t = blockIdx.x*256 + threadIdx.x;
  if (t < 3*128){
    int d = t >> 7, l = t & 127;
    wpq0[t] = (l < 64) ? (w1c[d*64 + l] - w1c[(d+3)*64 + l]) : w1c[(d+3)*64 + (l-64)];
  }
  if (t < 64*128){
    int d = t >> 7, l = t & 127;
    wpq1[t] = (l < 64) ? (w1d1[d*64 + l] - w1d1[(d+64)*64 + l]) : w1d1[(d+64)*64 + (l-64)];
    wpq2[t] = (l < 64) ? (w1d2[d*64 + l] - w1d2[(d+64)*64 + l]) : w1d2[(d+64)*64 + (l-64)];
  }
}

__global__ void zero_kernel(int* __restrict__ p){
  p[blockIdx.x*256 + threadIdx.x] = 0;
}

__global__ void init_enc_kernel(unsigned int* __restrict__ enc){
  enc[blockIdx.x*256 + threadIdx.x] = 0x007FFFFFu;   // enc(-inf)
}

// ---------- X[BN,D] @ wpq[D,128] -> P,Q
template<int D>
__global__ __launch_bounds__(128) void gemm_pq_kernel(const float* __restrict__ x,
                               const float* __restrict__ w,
                               float* __restrict__ P, float* __restrict__ Q){
  __shared__ float xs[8*D];
  int l = threadIdx.x;
  int node0 = blockIdx.x*8;
  float wc[D];
  #pragma unroll
  for (int d=0; d<D; d++) wc[d] = w[d*128 + l];
  for (int i=l; i < 8*D; i += 128) xs[i] = x[(size_t)node0*D + i];
  __syncthreads();
  #pragma unroll
  for (int n=0; n<8; n++){
    float s = 0.f;
    #pragma unroll
    for (int d=0; d<D; d++) s = fmaf(xs[n*D+d], wc[d], s);
    int node = node0 + n;
    if (l < 64) P[(size_t)node*64 + l] = s;
    else        Q[(size_t)node*64 + (l-64)] = s;
  }
}

// ---------- sq norms + bf16 copy of X
__global__ __launch_bounds__(256) void sqxb_kernel(const float* __restrict__ x,
        float* __restrict__ sq, unsigned short* __restrict__ xb){
  int t = blockIdx.x*256 + threadIdx.x;
  int node = t >> 6, l = t & 63;
  float v = x[t];
  unsigned u = __float_as_uint(v);
  xb[t] = (unsigned short)((u + 0x7FFFu + ((u >> 16) & 1u)) >> 16);  // RNE fp32->bf16
  float s = v*v;
  #pragma unroll
  for (int o=32; o; o>>=1) s += __shfl_xor(s, o, 64);
  if (l == 0) sq[node] = s;
}

// ---------- CSR build
__global__ void count_kernel(const int* __restrict__ ei, int* __restrict__ deg){
  int e = blockIdx.x*256 + threadIdx.x;
  atomicAdd(&deg[ei[En + e]], 1);
}

__global__ __launch_bounds__(1024) void scan_kernel(const int* __restrict__ deg,
        int* __restrict__ rowptr, int* __restrict__ cursor){
  __shared__ int ps[1024];
  int t = threadIdx.x;
  int base = t*64;
  int s = 0;
  for (int k=0;k<64;k++) s += deg[base+k];
  ps[t] = s; __syncthreads();
  for (int off=1; off<1024; off<<=1){
    int v = (t>=off) ? ps[t-off] : 0;
    __syncthreads();
    ps[t] += v;
    __syncthreads();
  }
  int run = (t>0) ? ps[t-1] : 0;
  for (int k=0;k<64;k++){
    rowptr[base+k] = run; cursor[base+k] = run;
    run += deg[base+k];
  }
  if (t==1023) rowptr[BNn] = run;
}

__global__ void scatter_kernel(const int* __restrict__ ei, int* __restrict__ cursor,
                               int* __restrict__ csrc, int* __restrict__ enid){
  int e = blockIdx.x*256 + threadIdx.x;
  int s = ei[e], d = ei[En + e];
  int pos = atomicAdd(&cursor[d], 1);
  csrc[pos] = s;
  enid[pos] = d;
}

// ---------- static EdgeConv as edge-batched GEMM (variable degree; CSR-ordered edges)
#define FMA8(av, r) \
  acc[r][0]=fmaf(av,b0.x,acc[r][0]); acc[r][1]=fmaf(av,b0.y,acc[r][1]); \
  acc[r][2]=fmaf(av,b0.z,acc[r][2]); acc[r][3]=fmaf(av,b0.w,acc[r][3]); \
  acc[r][4]=fmaf(av,b1v.x,acc[r][4]); acc[r][5]=fmaf(av,b1v.y,acc[r][5]); \
  acc[r][6]=fmaf(av,b1v.z,acc[r][6]); acc[r][7]=fmaf(av,b1v.w,acc[r][7]);

__global__ __launch_bounds__(256,3) void econv_gemm_kernel(
    const int* __restrict__ csrc, const int* __restrict__ enid,
    const float* __restrict__ P, const float* __restrict__ Q,
    const float* __restrict__ b1, const float* __restrict__ w2,
    unsigned int* __restrict__ enc){
  __shared__ __align__(16) float As[32*256];   // 32 KB (per k-half)
  __shared__ __align__(16) float Ws[64*64];    // 16 KB
  __shared__ int eids[256];
  int tid = threadIdx.x;
  int e0 = blockIdx.x*256;
  int e = e0 + tid;
  int j = csrc[e];
  int i = enid[e];
  eids[tid] = i;
  const float* Pr = P + (size_t)i*Hd;
  const float* Qr = Q + (size_t)j*Hd;
  #pragma unroll
  for (int c=0;c<16;c++) Ws[c*256 + tid] = w2[c*256 + tid];

  int m0 = tid >> 3, n0 = tid & 7;
  float acc[8][8];
  #pragma unroll
  for (int a=0;a<8;a++)
    #pragma unroll
    for (int b=0;b<8;b++) acc[a][b]=0.f;

  #pragma unroll 1
  for (int kh=0; kh<2; kh++){
    __syncthreads();   // Ws/eids ready (kh=0); previous half consumed (kh=1)
    #pragma unroll
    for (int c=0;c<8;c++){
      int k = kh*32 + 4*c;
      float4 q4 = *(const float4*)(Qr + k);
      float4 pk = *(const float4*)(Pr + k);
      float4 b4 = *(const float4*)(b1 + k);
      As[(4*c+0)*256 + tid] = fmaxf(pk.x+q4.x+b4.x, 0.f);
      As[(4*c+1)*256 + tid] = fmaxf(pk.y+q4.y+b4.y, 0.f);
      As[(4*c+2)*256 + tid] = fmaxf(pk.z+q4.z+b4.z, 0.f);
      As[(4*c+3)*256 + tid] = fmaxf(pk.w+q4.w+b4.w, 0.f);
    }
    __syncthreads();
    #pragma unroll 4
    for (int kk=0; kk<32; kk++){
      int k = kh*32 + kk;
      float4 a0 = *(const float4*)&As[kk*256 + 8*m0];
      float4 a1 = *(const float4*)&As[kk*256 + 8*m0 + 4];
      float4 b0 = *(const float4*)&Ws[k*64 + 8*n0];
      float4 b1v = *(const float4*)&Ws[k*64 + 8*n0 + 4];
      FMA8(a0.x, 0) FMA8(a0.y, 1) FMA8(a0.z, 2) FMA8(a0.w, 3)
      FMA8(a1.x, 4) FMA8(a1.y, 5) FMA8(a1.z, 6) FMA8(a1.w, 7)
    }
  }
  // epilogue: running max over this thread's 8 CSR rows, flush at node boundaries
  int rbase = 8*m0;
  int cur = eids[rbase];
  float vmax[8];
  #pragma unroll
  for (int b=0;b<8;b++) vmax[b] = -INFINITY;
  #pragma unroll
  for (int a=0;a<8;a++){
    int id = eids[rbase + a];
    if (id != cur){
      #pragma unroll
      for (int b=0;b<8;b++){
        unsigned u = __float_as_uint(vmax[b]);
        u = ((int)u < 0) ? ~u : (u | 0x80000000u);
        atomicMax(&enc[(size_t)cur*Hd + 8*n0 + b], u);
        vmax[b] = -INFINITY;
      }
      cur = id;
    }
    #pragma unroll
    for (int b=0;b<8;b++) vmax[b] = fmaxf(vmax[b], acc[a][b]);
  }
  #pragma unroll
  for (int b=0;b<8;b++){
    unsigned u = __float_as_uint(vmax[b]);
    u = ((int)u < 0) ? ~u : (u | 0x80000000u);
    atomicMax(&enc[(size_t)cur*Hd + 8*n0 + b], u);
  }
}

// ---------- kNN: bf16-MFMA approx distances + per-quarter top-24 (u32 keys)
__device__ __forceinline__ void ins24(unsigned (&kb)[KK], unsigned key){
  #pragma unroll
  for (int p=KK-1; p>0; p--){
    unsigned ins = (key < kb[p]) ? key : kb[p];
    kb[p] = (key < kb[p-1]) ? kb[p-1] : ins;
  }
  kb[0] = (key < kb[0]) ? key : kb[0];
}

__global__ __launch_bounds__(256,2) void knn_kernel(
    const unsigned short* __restrict__ xb, const float* __restrict__ sq,
    unsigned short* __restrict__ cand){
  __shared__ __align__(16) unsigned short xrb[64*72];    // rows, stride 72 u16
  __shared__ __align__(16) unsigned short xjb[128*72];   // j-tile
  __shared__ float Dt[64*133];                           // approx dist [row][col]
  __shared__ float sqs[128];
  __shared__ unsigned kc[CAPB][256];                     // u32 cand buffer, bank-safe

  int tid = threadIdx.x;
  int lane = tid & 63, w = tid >> 6;
  int g  = blockIdx.x >> 5;
  int r0 = (blockIdx.x & 31) * 64;
  const unsigned short* xbg = xb + (size_t)g*Ng*Hd;
  const float* sg = sq + (size_t)g*Ng;

  // stage xrb (64 rows x 64 bf16)
  {
    int r = tid >> 2, c = (tid & 3) * 16;
    const uint4* src = (const uint4*)(xbg + (size_t)(r0 + r)*Hd + c);
    uint4 a = src[0], b = src[1];
    *(uint4*)&xrb[r*72 + c]     = a;
    *(uint4*)&xrb[r*72 + c + 8] = b;
  }
  // stage xjb tile 0: xjb row jr <-> j = (jr>>5)*512 + (jr&31)
  {
    int jr = tid >> 1, half = tid & 1;
    int jloc = (jr >> 5)*512 + (jr & 31);
    const uint4* src = (const uint4*)(xbg + (size_t)jloc*Hd + half*32);
    uint4 a = src[0], b = src[1], c2 = src[2], d2 = src[3];
    uint4* dst = (uint4*)&xjb[jr*72 + half*32];
    dst[0]=a; dst[1]=b; dst[2]=c2; dst[3]=d2;
    if (tid < 128) sqs[tid] = sg[(tid>>5)*512 + (tid&31)];
  }

  unsigned kb[KK];
  #pragma unroll
  for (int t=0;t<KK;t++) kb[t] = 0xFFFFFFFFu;
  unsigned kbLast = 0xFFFFFFFFu;
  int cnt = 0;
  int q = w;           // Phase B quarter
  int prow = lane;     // Phase B row
  int rw = w*16;       // MFMA row-block base

  __syncthreads();

  // A fragments iter-invariant: hoist
  bf16x8 A0 = *(const bf16x8*)&xrb[(rw + (lane & 15))*72 +      (lane>>4)*8];
  bf16x8 A1 = *(const bf16x8*)&xrb[(rw + (lane & 15))*72 + 32 + (lane>>4)*8];

  #pragma unroll 1
  for (int it = 0; it < 16; it++){
    // prefetch next xjb into registers
    uint4 pf0, pf1, pf2, pf3; float psq = 0.f;
    int itn = it + 1;
    int jr = tid >> 1, half = tid & 1;
    if (itn < 16){
      int jloc = (jr >> 5)*512 + itn*32 + (jr & 31);
      const uint4* src = (const uint4*)(xbg + (size_t)jloc*Hd + half*32);
      pf0 = src[0]; pf1 = src[1]; pf2 = src[2]; pf3 = src[3];
      if (tid < 128) psq = sg[(tid>>5)*512 + itn*32 + (tid&31)];
    }
    // MFMA: 8 j-blocks x 2 k-chunks
    #pragma unroll
    for (int jb = 0; jb < 8; jb++){
      bf16x8 B0 = *(const bf16x8*)&xjb[(jb*16 + (lane & 15))*72 +      (lane>>4)*8];
      bf16x8 B1 = *(const bf16x8*)&xjb[(jb*16 + (lane & 15))*72 + 32 + (lane>>4)*8];
      f32x4 acc = {0.f, 0.f, 0.f, 0.f};
      acc = __builtin_amdgcn_mfma_f32_16x16x32_bf16(A0, B0, acc, 0, 0, 0);
      acc = __builtin_amdgcn_mfma_f32_16x16x32_bf16(A1, B1, acc, 0, 0, 0);
      int col = jb*16 + (lane & 15);       // C/D: col=lane&15, row=quad*4+v
      float sqv = sqs[col];
      int rbase = rw + (lane>>4)*4;
      #pragma unroll
      for (int v=0; v<4; v++)
        Dt[(rbase + v)*133 + col] = fmaf(acc[v], -2.f, sqv);
    }
    __syncthreads();   // Dt complete; xjb fully consumed
    // Phase B: lane scans 32 cols of its quarter; u32 keys (21b dist | 11b j)
    int jbase0 = q*512 + it*32;
    const float* drow = &Dt[prow*133 + q*32];
    #pragma unroll
    for (int i=0;i<32;i+=4){
      #pragma unroll
      for (int ii=0;ii<4;ii++){
        float s = drow[i+ii];
        unsigned u = __float_as_uint(s);
        u = ((int)u < 0) ? ~u : (u | 0x80000000u);
        unsigned key = (u & 0xFFFFF800u) | (unsigned)(jbase0 + i + ii);
        if (key < kbLast){ kc[cnt][tid] = key; cnt++; }
      }
      if (__any(cnt >= 4)){
        #pragma unroll 1
        for (int c=0;c<CAPB;c++){
          if (!__any(c < cnt)) break;
          unsigned k2 = (c < cnt) ? kc[c][tid] : 0xFFFFFFFFu;
          ins24(kb, k2);
        }
        cnt = 0; kbLast = kb[KK-1];
      }
    }
    // commit prefetched tile
    if (itn < 16){
      uint4* dst = (uint4*)&xjb[jr*72 + half*32];
      dst[0]=pf0; dst[1]=pf1; dst[2]=pf2; dst[3]=pf3;
      if (tid < 128) sqs[tid] = psq;
    }
    __syncthreads();
  }
  // final drain
  #pragma unroll 1
  for (int c=0;c<CAPB;c++){
    if (!__any(c < cnt)) break;
    unsigned k2 = (c < cnt) ? kc[c][tid] : 0xFFFFFFFFu;
    ins24(kb, k2);
  }
  // write 24 candidates (local j) for (row, quarter)
  size_t base = (size_t)(g*Ng + r0 + prow)*96 + q*24;
  #pragma unroll
  for (int t=0;t<KK;t++)
    cand[base + t] = (unsigned short)(kb[t] & 2047u);
}

// ---------- exact rerank: 4 rows/block; rank-popcount extraction
__global__ __launch_bounds__(256) void rerank_kernel(const float* __restrict__ x,
        const float* __restrict__ sq, const unsigned short* __restrict__ cand,
        int* __restrict__ idx){
  __shared__ __align__(16) float xrow[4][Hd];
  __shared__ __align__(16) unsigned long long ks[4][96];
  int tid = threadIdx.x;
  int lane = tid & 63, w = tid >> 6;
  int row = blockIdx.x*4 + w;
  int g = row >> 11;
  const float* xg = x + (size_t)g*Ng*Hd;
  const float* sg = sq + (size_t)g*Ng;
  xrow[w][lane] = x[(size_t)row*Hd + lane];
  __syncthreads();
  int j0 = cand[(size_t)row*96 + lane];
  int j1 = cand[(size_t)row*96 + 64 + (lane & 31)];
  const float* p0 = xg + (size_t)j0*Hd;
  const float* p1 = xg + (size_t)j1*Hd;
  float d0=0.f, e0=0.f, d1=0.f, e1=0.f;
  #pragma unroll
  for (int k=0;k<Hd;k+=4){
    float4 xr4 = *(const float4*)&xrow[w][k];
    float4 a = *(const float4*)(p0 + k);
    float4 b = *(const float4*)(p1 + k);
    d0 = fmaf(xr4.x, a.x, d0); e0 = fmaf(xr4.y, a.y, e0);
    d0 = fmaf(xr4.z, a.z, d0); e0 = fmaf(xr4.w, a.w, e0);
    d1 = fmaf(xr4.x, b.x, d1); e1 = fmaf(xr4.y, b.y, e1);
    d1 = fmaf(xr4.z, b.z, d1); e1 = fmaf(xr4.w, b.w, e1);
  }
  float dist0 = fmaf(d0 + e0, -2.f, sg[j0]);
  float dist1 = fmaf(d1 + e1, -2.f, sg[j1]);
  unsigned u0 = __float_as_uint(dist0);
  u0 = ((int)u0 < 0) ? ~u0 : (u0 | 0x80000000u);
  unsigned u1 = __float_as_uint(dist1);
  u1 = ((int)u1 < 0) ? ~u1 : (u1 | 0x80000000u);
  unsigned long long k0 = ((unsigned long long)u0 << 32) | (unsigned)j0;
  unsigned long long k1 = ((unsigned long long)u1 << 32) | (unsigned)j1;
  ks[w][lane] = k0;
  if (lane < 32) ks[w][64 + lane] = k1;
  __syncthreads();
  int r0 = 0, r1 = 0;
  #pragma unroll
  for (int c=0;c<96;c+=2){
    unsigned long long a = ks[w][c], b = ks[w][c+1];
    r0 += (a < k0) + (b < k0);
    r1 += (a < k1) + (b < k1);
  }
  if (r0 < Kn) idx[(size_t)row*Kn + r0] = g*Ng + j0;
  if (lane < 32 && r1 < Kn) idx[(size_t)row*Kn + r1] = g*Ng + j1;
}

// ---------- dynamic EdgeConv stage 2: edge-batched GEMM + node-max + atomicMax(enc)
__global__ __launch_bounds__(256,3) void emsg_kernel(
    const int* __restrict__ srcl,
    const float* __restrict__ P, const float* __restrict__ Q,
    const float* __restrict__ b1, const float* __restrict__ w2,
    unsigned int* __restrict__ enc){
  __shared__ __align__(16) char smem[49152];
  float* As = (float*)smem;                 // [32][256] (per k-half)
  float* Ws = (float*)(smem + 32768);       // [64][64]
  float* p0 = (float*)smem;                 // overlay: partial seg0 [64][33]
  float* p1 = (float*)(smem + 64*33*4);     // partial seg1 [64][33]
  int tid = threadIdx.x;
  int e0 = blockIdx.x * 256;
  int e = e0 + tid;
  int i = e / Kn;
  int j = srcl[e];
  const float* Pr = P + (size_t)i*Hd;
  const float* Qr = Q + (size_t)j*Hd;
  #pragma unroll
  for (int c=0;c<16;c++) Ws[c*256 + tid] = w2[c*256 + tid];

  int m0 = tid >> 3, n0 = tid & 7;
  float acc[8][8];
  #pragma unroll
  for (int a=0;a<8;a++)
    #pragma unroll
    for (int b=0;b<8;b++) acc[a][b]=0.f;

  #pragma unroll 1
  for (int kh=0; kh<2; kh++){
    __syncthreads();
    #pragma unroll
    for (int c=0;c<8;c++){
      int k = kh*32 + 4*c;
      float4 q4 = *(const float4*)(Qr + k);
      float4 pk = *(const float4*)(Pr + k);
      float4 b4 = *(const float4*)(b1 + k);
      As[(4*c+0)*256 + tid] = fmaxf(pk.x+q4.x+b4.x, 0.f);
      As[(4*c+1)*256 + tid] = fmaxf(pk.y+q4.y+b4.y, 0.f);
      As[(4*c+2)*256 + tid] = fmaxf(pk.z+q4.z+b4.z, 0.f);
      As[(4*c+3)*256 + tid] = fmaxf(pk.w+q4.w+b4.w, 0.f);
    }
    __syncthreads();
    #pragma unroll 4
    for (int kk=0; kk<32; kk++){
      int k = kh*32 + kk;
      float4 a0 = *(const float4*)&As[kk*256 + 8*m0];
      float4 a1 = *(const float4*)&As[kk*256 + 8*m0 + 4];
      float4 b0 = *(const float4*)&Ws[k*64 + 8*n0];
      float4 b1v = *(const float4*)&Ws[k*64 + 8*n0 + 4];
      FMA8(a0.x, 0) FMA8(a0.y, 1) FMA8(a0.z, 2) FMA8(a0.w, 3)
      FMA8(a1.x, 4) FMA8(a1.y, 5) FMA8(a1.z, 6) FMA8(a1.w, 7)
    }
  }
  int ebase = e0 + 8*m0;
  int nd0 = ebase / Kn;
  int split = (nd0+1)*Kn - ebase; if (split > 8) split = 8;
  float s0[8], s1[8];
  #pragma unroll
  for (int b=0;b<8;b++){ s0[b] = -INFINITY; s1[b] = -INFINITY; }
  #pragma unroll
  for (int a=0;a<8;a++)
    #pragma unroll
    for (int b=0;b<8;b++){
      if (a < split) s0[b] = fmaxf(s0[b], acc[a][b]);
      else           s1[b] = fmaxf(s1[b], acc[a][b]);
    }
  __syncthreads();
  #pragma unroll
  for (int b=0;b<8;b++){
    p0[(8*n0+b)*33 + m0] = s0[b];
    p1[(8*n0+b)*33 + m0] = s1[b];
  }
  __syncthreads();
  int nfirst = e0 / Kn;
  int ncnt = (e0 + 255) / Kn - nfirst + 1;
  int ch = tid & 63;
  for (int ln = tid >> 6; ln < ncnt; ln += 4){
    int nd = nfirst + ln;
    int glo = nd*Kn;      if (glo < e0)     glo = e0;
    int ghi = nd*Kn + Kn; if (ghi > e0+256) ghi = e0+256;
    int mlo = (glo - e0) >> 3, mhi = (ghi - 1 - e0) >> 3;
    float v = -INFINITY;
    for (int mm = mlo; mm <= mhi; mm++){
      int bn = (e0 + 8*mm) / Kn;
      if (bn == nd)     v = fmaxf(v, p0[ch*33 + mm]);
      if (bn + 1 == nd) v = fmaxf(v, p1[ch*33 + mm]);
    }
    unsigned u = __float_as_uint(v);
    u = ((int)u < 0) ? ~u : (u | 0x80000000u);
    atomicMax(&enc[(size_t)nd*Hd + ch], u);
  }
}

// ---------- decode: enc -> float, +b2, optional ELU
template<bool ELU>
__global__ __launch_bounds__(256) void decode_kernel(const unsigned int* __restrict__ enc,
         const float* __restrict__ b2, float* __restrict__ x){
  int t = blockIdx.x*256 + threadIdx.x;
  unsigned int e = enc[t];
  unsigned int bits = (e & 0x80000000u) ? (e ^ 0x80000000u) : ~e;
  float f = __uint_as_float(bits);
  if (isfinite(f)) f += b2[t & 63]; else f = 0.f;
  if (ELU) f = f > 0.f ? f : expm1f(f);
  x[t] = f;
}

__global__ __launch_bounds__(64) void final_kernel(const float* __restrict__ h,
        const float* __restrict__ w, const float* __restrict__ bias,
        float* __restrict__ out){
  __shared__ float xs[Hd];
  int c = threadIdx.x;
  float wc[Hd];
  float bc = 0.f;
  if (c < Cd){
    #pragma unroll
    for (int d=0; d<Hd; d++) wc[d] = w[d*Cd + c];
    bc = bias[c];
  }
  for (int i = blockIdx.x; i < BNn; i += gridDim.x){
    __syncthreads();
    xs[c] = h[(size_t)i*Hd + c];
    __syncthreads();
    if (c < Cd){
      float s = bc;
      #pragma unroll
      for (int d=0; d<Hd; d++) s = fmaf(xs[d], wc[d], s);
      out[(size_t)i*Cd + c] = s;
    }
  }
}

extern "C" void kernel_launch(void* const* d_in, const int* in_sizes, int n_in,
                              void* d_out, int out_size, void* d_ws, size_t ws_size,
                              hipStream_t stream){
  const float* x0   = (const float*)d_in[0];
  const int*   ei   = (const int*)d_in[1];
  const float* c1w1 = (const float*)d_in[3];
  const float* c1b1 = (const float*)d_in[4];
  const float* c1w2 = (const float*)d_in[5];
  const float* c1b2 = (const float*)d_in[6];
  const float* d1w1 = (const float*)d_in[7];
  const float* d1b1 = (const float*)d_in[8];
  const float* d1w2 = (const float*)d_in[9];
  const float* d1b2 = (const float*)d_in[10];
  const float* d2w1 = (const float*)d_in[11];
  const float* d2b1 = (const float*)d_in[12];
  const float* d2w2 = (const float*)d_in[13];
  const float* d2b2 = (const float*)d_in[14];
  const float* linw = (const float*)d_in[15];
  const float* linb = (const float*)d_in[16];
  float* out = (float*)d_out;

  char* ws = (char*)d_ws;
  size_t off = 0;
  auto alloc = [&](size_t bytes)->char*{
    char* p = ws + off; off += (bytes + 255) & ~(size_t)255; return p;
  };
  float*        X    = (float*)alloc(sizeof(float)*(size_t)BNn*Hd);
  float*        P    = (float*)alloc(sizeof(float)*(size_t)BNn*Hd);
  float*        Q    = (float*)alloc(sizeof(float)*(size_t)BNn*Hd);
  float*        H2   = (float*)alloc(sizeof(float)*(size_t)BNn*Hd);  // aliases XB, ENID
  unsigned int* ENC  = (unsigned int*)alloc(sizeof(unsigned)*(size_t)BNn*Hd); // aliases CAND
  int*          SHRD = (int*)alloc(sizeof(int)*(size_t)En);   // CSRC, later IDX
  int*          DEG  = (int*)alloc(sizeof(int)*BNn);
  int*          RPTR = (int*)alloc(sizeof(int)*(BNn+1));
  int*          CUR  = (int*)alloc(sizeof(int)*BNn);
  float*        SQ   = (float*)alloc(sizeof(float)*BNn);
  float*        WPQ0 = (float*)alloc(sizeof(float)*3*128);
  float*        WPQ1 = (float*)alloc(sizeof(float)*64*128);
  float*        WPQ2 = (float*)alloc(sizeof(float)*64*128);
  int*            CSRC = SHRD;
  int*            IDX  = SHRD;
  int*            ENID = (int*)H2;              // static phase only (E ints < BNn*Hd floats)
  unsigned short* XB   = (unsigned short*)H2;   // dead before decode writes H2
  unsigned short* CAND = (unsigned short*)ENC;  // dead before init_enc
  (void)ws_size; (void)in_sizes; (void)n_in; (void)out_size;

  // static EdgeConv: CSR sort + edge-batched GEMM + atomic max + decode
  prep_w_kernel<<<32, 256, 0, stream>>>(c1w1, d1w1, d2w1, WPQ0, WPQ1, WPQ2);
  zero_kernel<<<BNn/256, 256, 0, stream>>>(DEG);
  count_kernel<<<En/256, 256, 0, stream>>>(ei, DEG);
  gemm_pq_kernel<3><<<BNn/8, 128, 0, stream>>>(x0, WPQ0, P, Q);
  scan_kernel<<<1, 1024, 0, stream>>>(DEG, RPTR, CUR);
  scatter_kernel<<<En/256, 256, 0, stream>>>(ei, CUR, CSRC, ENID);
  init_enc_kernel<<<BNn*Hd/256, 256, 0, stream>>>(ENC);
  econv_gemm_kernel<<<En/256, 256, 0, stream>>>(CSRC, ENID, P, Q, c1b1, c1w2, ENC);
  decode_kernel<true><<<BNn*Hd/256, 256, 0, stream>>>(ENC, c1b2, X);

  // dynamic layer 1
  sqxb_kernel<<<BNn*Hd/256, 256, 0, stream>>>(X, SQ, XB);
  gemm_pq_kernel<64><<<BNn/8, 128, 0, stream>>>(X, WPQ1, P, Q);
  knn_kernel<<<Bg*32, 256, 0, stream>>>(XB, SQ, CAND);
  rerank_kernel<<<BNn/4, 256, 0, stream>>>(X, SQ, CAND, IDX);
  init_enc_kernel<<<BNn*Hd/256, 256, 0, stream>>>(ENC);
  emsg_kernel<<<En/256, 256, 0, stream>>>(IDX, P, Q, d1b1, d1w2, ENC);
  decode_kernel<true><<<BNn*Hd/256, 256, 0, stream>>>(ENC, d1b2, X);

  // dynamic layer 2
  sqxb_kernel<<<BNn*Hd/256, 256, 0, stream>>>(X, SQ, XB);
  gemm_pq_kernel<64><<<BNn/8, 128, 0, stream>>>(X, WPQ2, P, Q);
  knn_kernel<<<Bg*32, 256, 0, stream>>>(XB, SQ, CAND);
  rerank_kernel<<<BNn/4, 256, 0, stream>>>(X, SQ, CAND, IDX);
  init_enc_kernel<<<BNn*Hd/256, 256, 0, stream>>>(ENC);
  emsg_kernel<<<En/256, 256, 0, stream>>>(IDX, P, Q, d2b1, d2w2, ENC);
  decode_kernel<false><<<BNn*Hd/256, 256, 0, stream>>>(ENC, d2b2, H2);

  final_kernel<<<8192, 64, 0, stream>>>(H2, linw, linb, out);
}

// Round 10
// 1829.340 us; speedup vs baseline: 1.1232x; 1.1232x over previous
//
#include <hip/hip_runtime.h>
#include <math.h>

#define Bg 32
#define Ng 2048
#define Kn 20
#define BNn (Bg*Ng)
#define En (BNn*Kn)
#define Hd 64
#define Cd 40

// knn-mfma params
#define KK 24            // approx top-K kept per j-quarter (96 cands/row)
#define CAPB 8

typedef __attribute__((ext_vector_type(8))) short bf16x8;
typedef __attribute__((ext_vector_type(4))) float f32x4;

__device__ __forceinline__ unsigned enc_f32(float f){
  unsigned u = __float_as_uint(f);
  return ((int)u < 0) ? ~u : (u | 0x80000000u);
}

// ---------- weight prep
__global__ void prep_w_kernel(const float* __restrict__ w1c, const float* __restrict__ w1d1,
                              const float* __restrict__ w1d2,
                              float* __restrict__ wpq0, float* __restrict__ wpq1,
                              float* __restrict__ wpq2){
  int t = blockIdx.x*256 + threadIdx.x;
  if (t < 3*128){
    int d = t >> 7, l = t & 127;
    wpq0[t] = (l < 64) ? (w1c[d*64 + l] - w1c[(d+3)*64 + l]) : w1c[(d+3)*64 + (l-64)];
  }
  if (t < 64*128){
    int d = t >> 7, l = t & 127;
    wpq1[t] = (l < 64) ? (w1d1[d*64 + l] - w1d1[(d+64)*64 + l]) : w1d1[(d+64)*64 + (l-64)];
    wpq2[t] = (l < 64) ? (w1d2[d*64 + l] - w1d2[(d+64)*64 + l]) : w1d2[(d+64)*64 + (l-64)];
  }
}

__global__ void zero_kernel(int* __restrict__ p){
  p[blockIdx.x*256 + threadIdx.x] = 0;
}

__global__ void init_enc_kernel(unsigned int* __restrict__ enc){
  enc[blockIdx.x*256 + threadIdx.x] = 0x007FFFFFu;   // enc(-inf)
}

// ---------- X[BN,D] @ wpq[D,128] -> P,Q
template<int D>
__global__ __launch_bounds__(128) void gemm_pq_kernel(const float* __restrict__ x,
                               const float* __restrict__ w,
                               float* __restrict__ P, float* __restrict__ Q){
  __shared__ float xs[8*D];
  int l = threadIdx.x;
  int node0 = blockIdx.x*8;
  float wc[D];
  #pragma unroll
  for (int d=0; d<D; d++) wc[d] = w[d*128 + l];
  for (int i=l; i < 8*D; i += 128) xs[i] = x[(size_t)node0*D + i];
  __syncthreads();
  #pragma unroll
  for (int n=0; n<8; n++){
    float s = 0.f;
    #pragma unroll
    for (int d=0; d<D; d++) s = fmaf(xs[n*D+d], wc[d], s);
    int node = node0 + n;
    if (l < 64) P[(size_t)node*64 + l] = s;
    else        Q[(size_t)node*64 + (l-64)] = s;
  }
}

// ---------- sq norms + bf16 copy of X
__global__ __launch_bounds__(256) void sqxb_kernel(const float* __restrict__ x,
        float* __restrict__ sq, unsigned short* __restrict__ xb){
  int t = blockIdx.x*256 + threadIdx.x;
  int node = t >> 6, l = t & 63;
  float v = x[t];
  unsigned u = __float_as_uint(v);
  xb[t] = (unsigned short)((u + 0x7FFFu + ((u >> 16) & 1u)) >> 16);  // RNE fp32->bf16
  float s = v*v;
  #pragma unroll
  for (int o=32; o; o>>=1) s += __shfl_xor(s, o, 64);
  if (l == 0) sq[node] = s;
}

// ---------- CSR build
__global__ void count_kernel(const int* __restrict__ ei, int* __restrict__ deg){
  int e = blockIdx.x*256 + threadIdx.x;
  atomicAdd(&deg[ei[En + e]], 1);
}

__global__ __launch_bounds__(1024) void scan_kernel(const int* __restrict__ deg,
        int* __restrict__ rowptr, int* __restrict__ cursor){
  __shared__ int ps[1024];
  int t = threadIdx.x;
  int base = t*64;
  int s = 0;
  for (int k=0;k<64;k++) s += deg[base+k];
  ps[t] = s; __syncthreads();
  for (int off=1; off<1024; off<<=1){
    int v = (t>=off) ? ps[t-off] : 0;
    __syncthreads();
    ps[t] += v;
    __syncthreads();
  }
  int run = (t>0) ? ps[t-1] : 0;
  for (int k=0;k<64;k++){
    rowptr[base+k] = run; cursor[base+k] = run;
    run += deg[base+k];
  }
  if (t==1023) rowptr[BNn] = run;
}

__global__ void scatter_kernel(const int* __restrict__ ei, int* __restrict__ cursor,
                               int* __restrict__ csrc, int* __restrict__ enid){
  int e = blockIdx.x*256 + threadIdx.x;
  int s = ei[e], d = ei[En + e];
  int pos = atomicAdd(&cursor[d], 1);
  csrc[pos] = s;
  enid[pos] = d;
}

// ---------- static EdgeConv as edge-batched GEMM + LDS-reduced node-max epilogue
#define FMA8(av, r) \
  acc[r][0]=fmaf(av,b0.x,acc[r][0]); acc[r][1]=fmaf(av,b0.y,acc[r][1]); \
  acc[r][2]=fmaf(av,b0.z,acc[r][2]); acc[r][3]=fmaf(av,b0.w,acc[r][3]); \
  acc[r][4]=fmaf(av,b1v.x,acc[r][4]); acc[r][5]=fmaf(av,b1v.y,acc[r][5]); \
  acc[r][6]=fmaf(av,b1v.z,acc[r][6]); acc[r][7]=fmaf(av,b1v.w,acc[r][7]);

__global__ __launch_bounds__(256,3) void econv_gemm_kernel(
    const int* __restrict__ csrc, const int* __restrict__ enid,
    const float* __restrict__ P, const float* __restrict__ Q,
    const float* __restrict__ b1, const float* __restrict__ w2,
    unsigned int* __restrict__ enc){
  __shared__ __align__(16) float As[32*256];   // 32 KB (per k-half); lmax overlays after GEMM
  __shared__ __align__(16) float Ws[64*64];    // 16 KB
  __shared__ int eids[256];
  int tid = threadIdx.x;
  int e0 = blockIdx.x*256;
  int e = e0 + tid;
  int j = csrc[e];
  int i = enid[e];
  eids[tid] = i;
  const float* Pr = P + (size_t)i*Hd;
  const float* Qr = Q + (size_t)j*Hd;
  #pragma unroll
  for (int c=0;c<16;c++) Ws[c*256 + tid] = w2[c*256 + tid];

  int m0 = tid >> 3, n0 = tid & 7;
  float acc[8][8];
  #pragma unroll
  for (int a=0;a<8;a++)
    #pragma unroll
    for (int b=0;b<8;b++) acc[a][b]=0.f;

  #pragma unroll 1
  for (int kh=0; kh<2; kh++){
    __syncthreads();   // Ws/eids ready (kh=0); previous half consumed (kh=1)
    #pragma unroll
    for (int c=0;c<8;c++){
      int k = kh*32 + 4*c;
      float4 q4 = *(const float4*)(Qr + k);
      float4 pk = *(const float4*)(Pr + k);
      float4 b4 = *(const float4*)(b1 + k);
      As[(4*c+0)*256 + tid] = fmaxf(pk.x+q4.x+b4.x, 0.f);
      As[(4*c+1)*256 + tid] = fmaxf(pk.y+q4.y+b4.y, 0.f);
      As[(4*c+2)*256 + tid] = fmaxf(pk.z+q4.z+b4.z, 0.f);
      As[(4*c+3)*256 + tid] = fmaxf(pk.w+q4.w+b4.w, 0.f);
    }
    __syncthreads();
    #pragma unroll 4
    for (int kk=0; kk<32; kk++){
      int k = kh*32 + kk;
      float4 a0 = *(const float4*)&As[kk*256 + 8*m0];
      float4 a1 = *(const float4*)&As[kk*256 + 8*m0 + 4];
      float4 b0 = *(const float4*)&Ws[k*64 + 8*n0];
      float4 b1v = *(const float4*)&Ws[k*64 + 8*n0 + 4];
      FMA8(a0.x, 0) FMA8(a0.y, 1) FMA8(a0.z, 2) FMA8(a0.w, 3)
      FMA8(a1.x, 4) FMA8(a1.y, 5) FMA8(a1.z, 6) FMA8(a1.w, 7)
    }
  }
  // ---- epilogue: per-block LDS max table (overlay on dead As), 1 global atomic/(node,ch)
  unsigned* lmax = (unsigned*)As;        // [32][65] encoded-u32, stride 65 for bank spread
  int nfirst = eids[0];
  __syncthreads();                       // all waves done reading As
  for (int z = tid; z < 32*65; z += 256) lmax[z] = 0u;
  __syncthreads();
  {
    int rbase = 8*m0;
    int cur = eids[rbase];
    float vmax[8];
    #pragma unroll
    for (int b=0;b<8;b++) vmax[b] = -INFINITY;
    #pragma unroll
    for (int a=0;a<8;a++){
      int id = eids[rbase + a];
      if (id != cur){
        int lid = cur - nfirst;
        if (lid < 32){
          #pragma unroll
          for (int b=0;b<8;b++) atomicMax(&lmax[lid*65 + 8*n0 + b], enc_f32(vmax[b]));
        } else {
          #pragma unroll
          for (int b=0;b<8;b++) atomicMax(&enc[(size_t)cur*Hd + 8*n0 + b], enc_f32(vmax[b]));
        }
        #pragma unroll
        for (int b=0;b<8;b++) vmax[b] = -INFINITY;
        cur = id;
      }
      #pragma unroll
      for (int b=0;b<8;b++) vmax[b] = fmaxf(vmax[b], acc[a][b]);
    }
    int lid = cur - nfirst;
    if (lid < 32){
      #pragma unroll
      for (int b=0;b<8;b++) atomicMax(&lmax[lid*65 + 8*n0 + b], enc_f32(vmax[b]));
    } else {
      #pragma unroll
      for (int b=0;b<8;b++) atomicMax(&enc[(size_t)cur*Hd + 8*n0 + b], enc_f32(vmax[b]));
    }
  }
  __syncthreads();
  // flush touched entries: lanes = channels, waves stripe over lid
  {
    int ch = tid & 63;
    for (int lid = tid >> 6; lid < 32; lid += 4){
      unsigned v = lmax[lid*65 + ch];
      if (v) atomicMax(&enc[(size_t)(nfirst + lid)*Hd + ch], v);
    }
  }
}

// ---------- kNN: bf16-MFMA approx distances + per-quarter top-24 (u32 keys)
__device__ __forceinline__ void ins24(unsigned (&kb)[KK], unsigned key){
  #pragma unroll
  for (int p=KK-1; p>0; p--){
    unsigned ins = (key < kb[p]) ? key : kb[p];
    kb[p] = (key < kb[p-1]) ? kb[p-1] : ins;
  }
  kb[0] = (key < kb[0]) ? key : kb[0];
}

__global__ __launch_bounds__(256,2) void knn_kernel(
    const unsigned short* __restrict__ xb, const float* __restrict__ sq,
    unsigned short* __restrict__ cand){
  __shared__ __align__(16) unsigned short xrb[64*72];    // rows, stride 72 u16
  __shared__ __align__(16) unsigned short xjb[128*72];   // j-tile
  __shared__ float Dt[64*133];                           // approx dist [row][col]
  __shared__ float sqs[128];
  __shared__ unsigned kc[CAPB][256];                     // u32 cand buffer, bank-safe

  int tid = threadIdx.x;
  int lane = tid & 63, w = tid >> 6;
  int g  = blockIdx.x >> 5;
  int r0 = (blockIdx.x & 31) * 64;
  const unsigned short* xbg = xb + (size_t)g*Ng*Hd;
  const float* sg = sq + (size_t)g*Ng;

  // stage xrb (64 rows x 64 bf16)
  {
    int r = tid >> 2, c = (tid & 3) * 16;
    const uint4* src = (const uint4*)(xbg + (size_t)(r0 + r)*Hd + c);
    uint4 a = src[0], b = src[1];
    *(uint4*)&xrb[r*72 + c]     = a;
    *(uint4*)&xrb[r*72 + c + 8] = b;
  }
  // stage xjb tile 0: xjb row jr <-> j = (jr>>5)*512 + (jr&31)
  {
    int jr = tid >> 1, half = tid & 1;
    int jloc = (jr >> 5)*512 + (jr & 31);
    const uint4* src = (const uint4*)(xbg + (size_t)jloc*Hd + half*32);
    uint4 a = src[0], b = src[1], c2 = src[2], d2 = src[3];
    uint4* dst = (uint4*)&xjb[jr*72 + half*32];
    dst[0]=a; dst[1]=b; dst[2]=c2; dst[3]=d2;
    if (tid < 128) sqs[tid] = sg[(tid>>5)*512 + (tid&31)];
  }

  unsigned kb[KK];
  #pragma unroll
  for (int t=0;t<KK;t++) kb[t] = 0xFFFFFFFFu;
  unsigned kbLast = 0xFFFFFFFFu;
  int cnt = 0;
  int q = w;           // Phase B quarter
  int prow = lane;     // Phase B row
  int rw = w*16;       // MFMA row-block base

  __syncthreads();

  // A fragments iter-invariant: hoist
  bf16x8 A0 = *(const bf16x8*)&xrb[(rw + (lane & 15))*72 +      (lane>>4)*8];
  bf16x8 A1 = *(const bf16x8*)&xrb[(rw + (lane & 15))*72 + 32 + (lane>>4)*8];

  #pragma unroll 1
  for (int it = 0; it < 16; it++){
    // prefetch next xjb into registers
    uint4 pf0, pf1, pf2, pf3; float psq = 0.f;
    int itn = it + 1;
    int jr = tid >> 1, half = tid & 1;
    if (itn < 16){
      int jloc = (jr >> 5)*512 + itn*32 + (jr & 31);
      const uint4* src = (const uint4*)(xbg + (size_t)jloc*Hd + half*32);
      pf0 = src[0]; pf1 = src[1]; pf2 = src[2]; pf3 = src[3];
      if (tid < 128) psq = sg[(tid>>5)*512 + itn*32 + (tid&31)];
    }
    // MFMA: 8 j-blocks x 2 k-chunks
    #pragma unroll
    for (int jb = 0; jb < 8; jb++){
      bf16x8 B0 = *(const bf16x8*)&xjb[(jb*16 + (lane & 15))*72 +      (lane>>4)*8];
      bf16x8 B1 = *(const bf16x8*)&xjb[(jb*16 + (lane & 15))*72 + 32 + (lane>>4)*8];
      f32x4 acc = {0.f, 0.f, 0.f, 0.f};
      acc = __builtin_amdgcn_mfma_f32_16x16x32_bf16(A0, B0, acc, 0, 0, 0);
      acc = __builtin_amdgcn_mfma_f32_16x16x32_bf16(A1, B1, acc, 0, 0, 0);
      int col = jb*16 + (lane & 15);       // C/D: col=lane&15, row=quad*4+v
      float sqv = sqs[col];
      int rbase = rw + (lane>>4)*4;
      #pragma unroll
      for (int v=0; v<4; v++)
        Dt[(rbase + v)*133 + col] = fmaf(acc[v], -2.f, sqv);
    }
    __syncthreads();   // Dt complete; xjb fully consumed
    // Phase B: lane scans 32 cols of its quarter; u32 keys (21b dist | 11b j)
    int jbase0 = q*512 + it*32;
    const float* drow = &Dt[prow*133 + q*32];
    #pragma unroll
    for (int i=0;i<32;i+=4){
      #pragma unroll
      for (int ii=0;ii<4;ii++){
        float s = drow[i+ii];
        unsigned u = __float_as_uint(s);
        u = ((int)u < 0) ? ~u : (u | 0x80000000u);
        unsigned key = (u & 0xFFFFF800u) | (unsigned)(jbase0 + i + ii);
        if (key < kbLast){ kc[cnt][tid] = key; cnt++; }
      }
      if (__any(cnt >= 4)){
        #pragma unroll 1
        for (int c=0;c<CAPB;c++){
          if (!__any(c < cnt)) break;
          unsigned k2 = (c < cnt) ? kc[c][tid] : 0xFFFFFFFFu;
          ins24(kb, k2);
        }
        cnt = 0; kbLast = kb[KK-1];
      }
    }
    // commit prefetched tile
    if (itn < 16){
      uint4* dst = (uint4*)&xjb[jr*72 + half*32];
      dst[0]=pf0; dst[1]=pf1; dst[2]=pf2; dst[3]=pf3;
      if (tid < 128) sqs[tid] = psq;
    }
    __syncthreads();
  }
  // final drain
  #pragma unroll 1
  for (int c=0;c<CAPB;c++){
    if (!__any(c < cnt)) break;
    unsigned k2 = (c < cnt) ? kc[c][tid] : 0xFFFFFFFFu;
    ins24(kb, k2);
  }
  // write 24 candidates (local j) for (row, quarter)
  size_t base = (size_t)(g*Ng + r0 + prow)*96 + q*24;
  #pragma unroll
  for (int t=0;t<KK;t++)
    cand[base + t] = (unsigned short)(kb[t] & 2047u);
}

// ---------- exact rerank: 4 rows/block; rank-popcount extraction
__global__ __launch_bounds__(256) void rerank_kernel(const float* __restrict__ x,
        const float* __restrict__ sq, const unsigned short* __restrict__ cand,
        int* __restrict__ idx){
  __shared__ __align__(16) float xrow[4][Hd];
  __shared__ __align__(16) unsigned long long ks[4][96];
  int tid = threadIdx.x;
  int lane = tid & 63, w = tid >> 6;
  int row = blockIdx.x*4 + w;
  int g = row >> 11;
  const float* xg = x + (size_t)g*Ng*Hd;
  const float* sg = sq + (size_t)g*Ng;
  xrow[w][lane] = x[(size_t)row*Hd + lane];
  __syncthreads();
  int j0 = cand[(size_t)row*96 + lane];
  int j1 = cand[(size_t)row*96 + 64 + (lane & 31)];
  const float* p0 = xg + (size_t)j0*Hd;
  const float* p1 = xg + (size_t)j1*Hd;
  float d0=0.f, e0=0.f, d1=0.f, e1=0.f;
  #pragma unroll
  for (int k=0;k<Hd;k+=4){
    float4 xr4 = *(const float4*)&xrow[w][k];
    float4 a = *(const float4*)(p0 + k);
    float4 b = *(const float4*)(p1 + k);
    d0 = fmaf(xr4.x, a.x, d0); e0 = fmaf(xr4.y, a.y, e0);
    d0 = fmaf(xr4.z, a.z, d0); e0 = fmaf(xr4.w, a.w, e0);
    d1 = fmaf(xr4.x, b.x, d1); e1 = fmaf(xr4.y, b.y, e1);
    d1 = fmaf(xr4.z, b.z, d1); e1 = fmaf(xr4.w, b.w, e1);
  }
  float dist0 = fmaf(d0 + e0, -2.f, sg[j0]);
  float dist1 = fmaf(d1 + e1, -2.f, sg[j1]);
  unsigned u0 = enc_f32(dist0);
  unsigned u1 = enc_f32(dist1);
  unsigned long long k0 = ((unsigned long long)u0 << 32) | (unsigned)j0;
  unsigned long long k1 = ((unsigned long long)u1 << 32) | (unsigned)j1;
  ks[w][lane] = k0;
  if (lane < 32) ks[w][64 + lane] = k1;
  __syncthreads();
  int r0 = 0, r1 = 0;
  #pragma unroll
  for (int c=0;c<96;c+=2){
    unsigned long long a = ks[w][c], b = ks[w][c+1];
    r0 += (a < k0) + (b < k0);
    r1 += (a < k1) + (b < k1);
  }
  if (r0 < Kn) idx[(size_t)row*Kn + r0] = g*Ng + j0;
  if (lane < 32 && r1 < Kn) idx[(size_t)row*Kn + r1] = g*Ng + j1;
}

// ---------- dynamic EdgeConv stage 2: edge-batched GEMM + node-max + atomicMax(enc)
__global__ __launch_bounds__(256,3) void emsg_kernel(
    const int* __restrict__ srcl,
    const float* __restrict__ P, const float* __restrict__ Q,
    const float* __restrict__ b1, const float* __restrict__ w2,
    unsigned int* __restrict__ enc){
  __shared__ __align__(16) char smem[49152];
  float* As = (float*)smem;                 // [32][256] (per k-half)
  float* Ws = (float*)(smem + 32768);       // [64][64]
  float* p0 = (float*)smem;                 // overlay: partial seg0 [64][33]
  float* p1 = (float*)(smem + 64*33*4);     // partial seg1 [64][33]
  int tid = threadIdx.x;
  int e0 = blockIdx.x * 256;
  int e = e0 + tid;
  int i = e / Kn;
  int j = srcl[e];
  const float* Pr = P + (size_t)i*Hd;
  const float* Qr = Q + (size_t)j*Hd;
  #pragma unroll
  for (int c=0;c<16;c++) Ws[c*256 + tid] = w2[c*256 + tid];

  int m0 = tid >> 3, n0 = tid & 7;
  float acc[8][8];
  #pragma unroll
  for (int a=0;a<8;a++)
    #pragma unroll
    for (int b=0;b<8;b++) acc[a][b]=0.f;

  #pragma unroll 1
  for (int kh=0; kh<2; kh++){
    __syncthreads();
    #pragma unroll
    for (int c=0;c<8;c++){
      int k = kh*32 + 4*c;
      float4 q4 = *(const float4*)(Qr + k);
      float4 pk = *(const float4*)(Pr + k);
      float4 b4 = *(const float4*)(b1 + k);
      As[(4*c+0)*256 + tid] = fmaxf(pk.x+q4.x+b4.x, 0.f);
      As[(4*c+1)*256 + tid] = fmaxf(pk.y+q4.y+b4.y, 0.f);
      As[(4*c+2)*256 + tid] = fmaxf(pk.z+q4.z+b4.z, 0.f);
      As[(4*c+3)*256 + tid] = fmaxf(pk.w+q4.w+b4.w, 0.f);
    }
    __syncthreads();
    #pragma unroll 4
    for (int kk=0; kk<32; kk++){
      int k = kh*32 + kk;
      float4 a0 = *(const float4*)&As[kk*256 + 8*m0];
      float4 a1 = *(const float4*)&As[kk*256 + 8*m0 + 4];
      float4 b0 = *(const float4*)&Ws[k*64 + 8*n0];
      float4 b1v = *(const float4*)&Ws[k*64 + 8*n0 + 4];
      FMA8(a0.x, 0) FMA8(a0.y, 1) FMA8(a0.z, 2) FMA8(a0.w, 3)
      FMA8(a1.x, 4) FMA8(a1.y, 5) FMA8(a1.z, 6) FMA8(a1.w, 7)
    }
  }
  int ebase = e0 + 8*m0;
  int nd0 = ebase / Kn;
  int split = (nd0+1)*Kn - ebase; if (split > 8) split = 8;
  float s0[8], s1[8];
  #pragma unroll
  for (int b=0;b<8;b++){ s0[b] = -INFINITY; s1[b] = -INFINITY; }
  #pragma unroll
  for (int a=0;a<8;a++)
    #pragma unroll
    for (int b=0;b<8;b++){
      if (a < split) s0[b] = fmaxf(s0[b], acc[a][b]);
      else           s1[b] = fmaxf(s1[b], acc[a][b]);
    }
  __syncthreads();
  #pragma unroll
  for (int b=0;b<8;b++){
    p0[(8*n0+b)*33 + m0] = s0[b];
    p1[(8*n0+b)*33 + m0] = s1[b];
  }
  __syncthreads();
  int nfirst = e0 / Kn;
  int ncnt = (e0 + 255) / Kn - nfirst + 1;
  int ch = tid & 63;
  for (int ln = tid >> 6; ln < ncnt; ln += 4){
    int nd = nfirst + ln;
    int glo = nd*Kn;      if (glo < e0)     glo = e0;
    int ghi = nd*Kn + Kn; if (ghi > e0+256) ghi = e0+256;
    int mlo = (glo - e0) >> 3, mhi = (ghi - 1 - e0) >> 3;
    float v = -INFINITY;
    for (int mm = mlo; mm <= mhi; mm++){
      int bn = (e0 + 8*mm) / Kn;
      if (bn == nd)     v = fmaxf(v, p0[ch*33 + mm]);
      if (bn + 1 == nd) v = fmaxf(v, p1[ch*33 + mm]);
    }
    atomicMax(&enc[(size_t)nd*Hd + ch], enc_f32(v));
  }
}

// ---------- decode: enc -> float, +b2, optional ELU
template<bool ELU>
__global__ __launch_bounds__(256) void decode_kernel(const unsigned int* __restrict__ enc,
         const float* __restrict__ b2, float* __restrict__ x){
  int t = blockIdx.x*256 + threadIdx.x;
  unsigned int e = enc[t];
  unsigned int bits = (e & 0x80000000u) ? (e ^ 0x80000000u) : ~e;
  float f = __uint_as_float(bits);
  if (isfinite(f)) f += b2[t & 63]; else f = 0.f;
  if (ELU) f = f > 0.f ? f : expm1f(f);
  x[t] = f;
}

__global__ __launch_bounds__(64) void final_kernel(const float* __restrict__ h,
        const float* __restrict__ w, const float* __restrict__ bias,
        float* __restrict__ out){
  __shared__ float xs[Hd];
  int c = threadIdx.x;
  float wc[Hd];
  float bc = 0.f;
  if (c < Cd){
    #pragma unroll
    for (int d=0; d<Hd; d++) wc[d] = w[d*Cd + c];
    bc = bias[c];
  }
  for (int i = blockIdx.x; i < BNn; i += gridDim.x){
    __syncthreads();
    xs[c] = h[(size_t)i*Hd + c];
    __syncthreads();
    if (c < Cd){
      float s = bc;
      #pragma unroll
      for (int d=0; d<Hd; d++) s = fmaf(xs[d], wc[d], s);
      out[(size_t)i*Cd + c] = s;
    }
  }
}

extern "C" void kernel_launch(void* const* d_in, const int* in_sizes, int n_in,
                              void* d_out, int out_size, void* d_ws, size_t ws_size,
                              hipStream_t stream){
  const float* x0   = (const float*)d_in[0];
  const int*   ei   = (const int*)d_in[1];
  const float* c1w1 = (const float*)d_in[3];
  const float* c1b1 = (const float*)d_in[4];
  const float* c1w2 = (const float*)d_in[5];
  const float* c1b2 = (const float*)d_in[6];
  const float* d1w1 = (const float*)d_in[7];
  const float* d1b1 = (const float*)d_in[8];
  const float* d1w2 = (const float*)d_in[9];
  const float* d1b2 = (const float*)d_in[10];
  const float* d2w1 = (const float*)d_in[11];
  const float* d2b1 = (const float*)d_in[12];
  const float* d2w2 = (const float*)d_in[13];
  const float* d2b2 = (const float*)d_in[14];
  const float* linw = (const float*)d_in[15];
  const float* linb = (const float*)d_in[16];
  float* out = (float*)d_out;

  char* ws = (char*)d_ws;
  size_t off = 0;
  auto alloc = [&](size_t bytes)->char*{
    char* p = ws + off; off += (bytes + 255) & ~(size_t)255; return p;
  };
  float*        X    = (float*)alloc(sizeof(float)*(size_t)BNn*Hd);
  float*        P    = (float*)alloc(sizeof(float)*(size_t)BNn*Hd);
  float*        Q    = (float*)alloc(sizeof(float)*(size_t)BNn*Hd);
  float*        H2   = (float*)alloc(sizeof(float)*(size_t)BNn*Hd);  // aliases XB, ENID
  unsigned int* ENC  = (unsigned int*)alloc(sizeof(unsigned)*(size_t)BNn*Hd); // aliases CAND
  int*          SHRD = (int*)alloc(sizeof(int)*(size_t)En);   // CSRC, later IDX
  int*          DEG  = (int*)alloc(sizeof(int)*BNn);
  int*          RPTR = (int*)alloc(sizeof(int)*(BNn+1));
  int*          CUR  = (int*)alloc(sizeof(int)*BNn);
  float*        SQ   = (float*)alloc(sizeof(float)*BNn);
  float*        WPQ0 = (float*)alloc(sizeof(float)*3*128);
  float*        WPQ1 = (float*)alloc(sizeof(float)*64*128);
  float*        WPQ2 = (float*)alloc(sizeof(float)*64*128);
  int*            CSRC = SHRD;
  int*            IDX  = SHRD;
  int*            ENID = (int*)H2;              // static phase only
  unsigned short* XB   = (unsigned short*)H2;   // dead before decode writes H2
  unsigned short* CAND = (unsigned short*)ENC;  // dead before init_enc
  (void)ws_size; (void)in_sizes; (void)n_in; (void)out_size;

  // static EdgeConv: CSR sort + edge-batched GEMM + LDS-reduced max + decode
  prep_w_kernel<<<32, 256, 0, stream>>>(c1w1, d1w1, d2w1, WPQ0, WPQ1, WPQ2);
  zero_kernel<<<BNn/256, 256, 0, stream>>>(DEG);
  count_kernel<<<En/256, 256, 0, stream>>>(ei, DEG);
  gemm_pq_kernel<3><<<BNn/8, 128, 0, stream>>>(x0, WPQ0, P, Q);
  scan_kernel<<<1, 1024, 0, stream>>>(DEG, RPTR, CUR);
  scatter_kernel<<<En/256, 256, 0, stream>>>(ei, CUR, CSRC, ENID);
  init_enc_kernel<<<BNn*Hd/256, 256, 0, stream>>>(ENC);
  econv_gemm_kernel<<<En/256, 256, 0, stream>>>(CSRC, ENID, P, Q, c1b1, c1w2, ENC);
  decode_kernel<true><<<BNn*Hd/256, 256, 0, stream>>>(ENC, c1b2, X);

  // dynamic layer 1
  sqxb_kernel<<<BNn*Hd/256, 256, 0, stream>>>(X, SQ, XB);
  gemm_pq_kernel<64><<<BNn/8, 128, 0, stream>>>(X, WPQ1, P, Q);
  knn_kernel<<<Bg*32, 256, 0, stream>>>(XB, SQ, CAND);
  rerank_kernel<<<BNn/4, 256, 0, stream>>>(X, SQ, CAND, IDX);
  init_enc_kernel<<<BNn*Hd/256, 256, 0, stream>>>(ENC);
  emsg_kernel<<<En/256, 256, 0, stream>>>(IDX, P, Q, d1b1, d1w2, ENC);
  decode_kernel<true><<<BNn*Hd/256, 256, 0, stream>>>(ENC, d1b2, X);

  // dynamic layer 2
  sqxb_kernel<<<BNn*Hd/256, 256, 0, stream>>>(X, SQ, XB);
  gemm_pq_kernel<64><<<BNn/8, 128, 0, stream>>>(X, WPQ2, P, Q);
  knn_kernel<<<Bg*32, 256, 0, stream>>>(XB, SQ, CAND);
  rerank_kernel<<<BNn/4, 256, 0, stream>>>(X, SQ, CAND, IDX);
  init_enc_kernel<<<BNn*Hd/256, 256, 0, stream>>>(ENC);
  emsg_kernel<<<En/256, 256, 0, stream>>>(IDX, P, Q, d2b1, d2w2, ENC);
  decode_kernel<false><<<BNn*Hd/256, 256, 0, stream>>>(ENC, d2b2, H2);

  final_kernel<<<8192, 64, 0, stream>>>(H2, linw, linb, out);
}

// Round 11
// 1691.729 us; speedup vs baseline: 1.2146x; 1.0813x over previous
//
#include <hip/hip_runtime.h>
#include <math.h>

#define Bg 32
#define Ng 2048
#define Kn 20
#define BNn (Bg*Ng)
#define En (BNn*Kn)
#define Hd 64
#define Cd 40

// knn-mfma params
#define KK 24            // approx top-K kept per j-quarter (96 cands/row)
#define CAPB 8

typedef __attribute__((ext_vector_type(8))) short bf16x8;
typedef __attribute__((ext_vector_type(4))) float f32x4;

__device__ __forceinline__ unsigned enc_f32(float f){
  unsigned u = __float_as_uint(f);
  return ((int)u < 0) ? ~u : (u | 0x80000000u);
}

// ---------- weight prep
__global__ void prep_w_kernel(const float* __restrict__ w1c, const float* __restrict__ w1d1,
                              const float* __restrict__ w1d2,
                              float* __restrict__ wpq0, float* __restrict__ wpq1,
                              float* __restrict__ wpq2){
  int t = blockIdx.x*256 + threadIdx.x;
  if (t < 3*128){
    int d = t >> 7, l = t & 127;
    wpq0[t] = (l < 64) ? (w1c[d*64 + l] - w1c[(d+3)*64 + l]) : w1c[(d+3)*64 + (l-64)];
  }
  if (t < 64*128){
    int d = t >> 7, l = t & 127;
    wpq1[t] = (l < 64) ? (w1d1[d*64 + l] - w1d1[(d+64)*64 + l]) : w1d1[(d+64)*64 + (l-64)];
    wpq2[t] = (l < 64) ? (w1d2[d*64 + l] - w1d2[(d+64)*64 + l]) : w1d2[(d+64)*64 + (l-64)];
  }
}

__global__ void zero_kernel(int* __restrict__ p){
  p[blockIdx.x*256 + threadIdx.x] = 0;
}

__global__ void init_enc_kernel(unsigned int* __restrict__ enc){
  enc[blockIdx.x*256 + threadIdx.x] = 0x007FFFFFu;   // enc(-inf)
}

// ---------- X[BN,D] @ wpq[D,128] -> P,Q
template<int D>
__global__ __launch_bounds__(128) void gemm_pq_kernel(const float* __restrict__ x,
                               const float* __restrict__ w,
                               float* __restrict__ P, float* __restrict__ Q){
  __shared__ float xs[8*D];
  int l = threadIdx.x;
  int node0 = blockIdx.x*8;
  float wc[D];
  #pragma unroll
  for (int d=0; d<D; d++) wc[d] = w[d*128 + l];
  for (int i=l; i < 8*D; i += 128) xs[i] = x[(size_t)node0*D + i];
  __syncthreads();
  #pragma unroll
  for (int n=0; n<8; n++){
    float s = 0.f;
    #pragma unroll
    for (int d=0; d<D; d++) s = fmaf(xs[n*D+d], wc[d], s);
    int node = node0 + n;
    if (l < 64) P[(size_t)node*64 + l] = s;
    else        Q[(size_t)node*64 + (l-64)] = s;
  }
}

// ---------- sq norms + bf16 copy of X (first static layer input path)
__global__ __launch_bounds__(256) void sqxb_kernel(const float* __restrict__ x,
        float* __restrict__ sq, unsigned short* __restrict__ xb){
  int t = blockIdx.x*256 + threadIdx.x;
  int node = t >> 6, l = t & 63;
  float v = x[t];
  unsigned u = __float_as_uint(v);
  xb[t] = (unsigned short)((u + 0x7FFFu + ((u >> 16) & 1u)) >> 16);  // RNE fp32->bf16
  float s = v*v;
  #pragma unroll
  for (int o=32; o; o>>=1) s += __shfl_xor(s, o, 64);
  if (l == 0) sq[node] = s;
}

// ---------- fused decode(+b2,+ELU) -> X, bf16 XB, SQ
__global__ __launch_bounds__(256) void decode_sqxb_kernel(const unsigned int* __restrict__ enc,
        const float* __restrict__ b2, float* __restrict__ x,
        float* __restrict__ sq, unsigned short* __restrict__ xb){
  int t = blockIdx.x*256 + threadIdx.x;
  int node = t >> 6, l = t & 63;
  unsigned int e = enc[t];
  unsigned int bits = (e & 0x80000000u) ? (e ^ 0x80000000u) : ~e;
  float f = __uint_as_float(bits);
  if (isfinite(f)) f += b2[l]; else f = 0.f;
  f = f > 0.f ? f : expm1f(f);
  x[t] = f;
  unsigned u = __float_as_uint(f);
  xb[t] = (unsigned short)((u + 0x7FFFu + ((u >> 16) & 1u)) >> 16);
  float s = f*f;
  #pragma unroll
  for (int o=32; o; o>>=1) s += __shfl_xor(s, o, 64);
  if (l == 0) sq[node] = s;
}

// ---------- CSR build
__global__ void count_kernel(const int* __restrict__ ei, int* __restrict__ deg){
  int e = blockIdx.x*256 + threadIdx.x;
  atomicAdd(&deg[ei[En + e]], 1);
}

__global__ __launch_bounds__(1024) void scan_kernel(const int* __restrict__ deg,
        int* __restrict__ rowptr, int* __restrict__ cursor){
  __shared__ int ps[1024];
  int t = threadIdx.x;
  int base = t*64;
  int s = 0;
  for (int k=0;k<64;k++) s += deg[base+k];
  ps[t] = s; __syncthreads();
  for (int off=1; off<1024; off<<=1){
    int v = (t>=off) ? ps[t-off] : 0;
    __syncthreads();
    ps[t] += v;
    __syncthreads();
  }
  int run = (t>0) ? ps[t-1] : 0;
  for (int k=0;k<64;k++){
    rowptr[base+k] = run; cursor[base+k] = run;
    run += deg[base+k];
  }
  if (t==1023) rowptr[BNn] = run;
}

__global__ void scatter_kernel(const int* __restrict__ ei, int* __restrict__ cursor,
                               int* __restrict__ csrc, int* __restrict__ enid){
  int e = blockIdx.x*256 + threadIdx.x;
  int s = ei[e], d = ei[En + e];
  int pos = atomicAdd(&cursor[d], 1);
  csrc[pos] = s;
  enid[pos] = d;
}

// ---------- static EdgeConv as edge-batched GEMM + LDS-reduced node-max epilogue
#define FMA8(av, r) \
  acc[r][0]=fmaf(av,b0.x,acc[r][0]); acc[r][1]=fmaf(av,b0.y,acc[r][1]); \
  acc[r][2]=fmaf(av,b0.z,acc[r][2]); acc[r][3]=fmaf(av,b0.w,acc[r][3]); \
  acc[r][4]=fmaf(av,b1v.x,acc[r][4]); acc[r][5]=fmaf(av,b1v.y,acc[r][5]); \
  acc[r][6]=fmaf(av,b1v.z,acc[r][6]); acc[r][7]=fmaf(av,b1v.w,acc[r][7]);

__global__ __launch_bounds__(256,3) void econv_gemm_kernel(
    const int* __restrict__ csrc, const int* __restrict__ enid,
    const float* __restrict__ P, const float* __restrict__ Q,
    const float* __restrict__ b1, const float* __restrict__ w2,
    unsigned int* __restrict__ enc){
  __shared__ __align__(16) float As[32*256];   // 32 KB (per k-half); lmax overlays after GEMM
  __shared__ __align__(16) float Ws[64*64];    // 16 KB
  __shared__ int eids[256];
  int tid = threadIdx.x;
  int e0 = blockIdx.x*256;
  int e = e0 + tid;
  int j = csrc[e];
  int i = enid[e];
  eids[tid] = i;
  const float* Pr = P + (size_t)i*Hd;
  const float* Qr = Q + (size_t)j*Hd;
  #pragma unroll
  for (int c=0;c<16;c++) Ws[c*256 + tid] = w2[c*256 + tid];

  int m0 = tid >> 3, n0 = tid & 7;
  float acc[8][8];
  #pragma unroll
  for (int a=0;a<8;a++)
    #pragma unroll
    for (int b=0;b<8;b++) acc[a][b]=0.f;

  #pragma unroll 1
  for (int kh=0; kh<2; kh++){
    __syncthreads();
    #pragma unroll
    for (int c=0;c<8;c++){
      int k = kh*32 + 4*c;
      float4 q4 = *(const float4*)(Qr + k);
      float4 pk = *(const float4*)(Pr + k);
      float4 b4 = *(const float4*)(b1 + k);
      As[(4*c+0)*256 + tid] = fmaxf(pk.x+q4.x+b4.x, 0.f);
      As[(4*c+1)*256 + tid] = fmaxf(pk.y+q4.y+b4.y, 0.f);
      As[(4*c+2)*256 + tid] = fmaxf(pk.z+q4.z+b4.z, 0.f);
      As[(4*c+3)*256 + tid] = fmaxf(pk.w+q4.w+b4.w, 0.f);
    }
    __syncthreads();
    #pragma unroll 4
    for (int kk=0; kk<32; kk++){
      int k = kh*32 + kk;
      float4 a0 = *(const float4*)&As[kk*256 + 8*m0];
      float4 a1 = *(const float4*)&As[kk*256 + 8*m0 + 4];
      float4 b0 = *(const float4*)&Ws[k*64 + 8*n0];
      float4 b1v = *(const float4*)&Ws[k*64 + 8*n0 + 4];
      FMA8(a0.x, 0) FMA8(a0.y, 1) FMA8(a0.z, 2) FMA8(a0.w, 3)
      FMA8(a1.x, 4) FMA8(a1.y, 5) FMA8(a1.z, 6) FMA8(a1.w, 7)
    }
  }
  // ---- epilogue: per-block LDS max table, 1 global atomic/(node,ch)
  unsigned* lmax = (unsigned*)As;        // [32][65]
  int nfirst = eids[0];
  __syncthreads();
  for (int z = tid; z < 32*65; z += 256) lmax[z] = 0u;
  __syncthreads();
  {
    int rbase = 8*m0;
    int cur = eids[rbase];
    float vmax[8];
    #pragma unroll
    for (int b=0;b<8;b++) vmax[b] = -INFINITY;
    #pragma unroll
    for (int a=0;a<8;a++){
      int id = eids[rbase + a];
      if (id != cur){
        int lid = cur - nfirst;
        if (lid < 32){
          #pragma unroll
          for (int b=0;b<8;b++) atomicMax(&lmax[lid*65 + 8*n0 + b], enc_f32(vmax[b]));
        } else {
          #pragma unroll
          for (int b=0;b<8;b++) atomicMax(&enc[(size_t)cur*Hd + 8*n0 + b], enc_f32(vmax[b]));
        }
        #pragma unroll
        for (int b=0;b<8;b++) vmax[b] = -INFINITY;
        cur = id;
      }
      #pragma unroll
      for (int b=0;b<8;b++) vmax[b] = fmaxf(vmax[b], acc[a][b]);
    }
    int lid = cur - nfirst;
    if (lid < 32){
      #pragma unroll
      for (int b=0;b<8;b++) atomicMax(&lmax[lid*65 + 8*n0 + b], enc_f32(vmax[b]));
    } else {
      #pragma unroll
      for (int b=0;b<8;b++) atomicMax(&enc[(size_t)cur*Hd + 8*n0 + b], enc_f32(vmax[b]));
    }
  }
  __syncthreads();
  {
    int ch = tid & 63;
    for (int lid = tid >> 6; lid < 32; lid += 4){
      unsigned v = lmax[lid*65 + ch];
      if (v) atomicMax(&enc[(size_t)(nfirst + lid)*Hd + ch], v);
    }
  }
}

// ---------- kNN: bf16-MFMA approx distances + per-quarter top-24 (u32 keys)
__device__ __forceinline__ void ins24(unsigned (&kb)[KK], unsigned key){
  #pragma unroll
  for (int p=KK-1; p>0; p--){
    unsigned ins = (key < kb[p]) ? key : kb[p];
    kb[p] = (key < kb[p-1]) ? kb[p-1] : ins;
  }
  kb[0] = (key < kb[0]) ? key : kb[0];
}

__global__ __launch_bounds__(256,2) void knn_kernel(
    const unsigned short* __restrict__ xb, const float* __restrict__ sq,
    unsigned short* __restrict__ cand){
  __shared__ __align__(16) unsigned short xrb[64*72];
  __shared__ __align__(16) unsigned short xjb[128*72];
  __shared__ float Dt[64*133];
  __shared__ float sqs[128];
  __shared__ unsigned kc[CAPB][256];

  int tid = threadIdx.x;
  int lane = tid & 63, w = tid >> 6;
  int g  = blockIdx.x >> 5;
  int r0 = (blockIdx.x & 31) * 64;
  const unsigned short* xbg = xb + (size_t)g*Ng*Hd;
  const float* sg = sq + (size_t)g*Ng;

  {
    int r = tid >> 2, c = (tid & 3) * 16;
    const uint4* src = (const uint4*)(xbg + (size_t)(r0 + r)*Hd + c);
    uint4 a = src[0], b = src[1];
    *(uint4*)&xrb[r*72 + c]     = a;
    *(uint4*)&xrb[r*72 + c + 8] = b;
  }
  {
    int jr = tid >> 1, half = tid & 1;
    int jloc = (jr >> 5)*512 + (jr & 31);
    const uint4* src = (const uint4*)(xbg + (size_t)jloc*Hd + half*32);
    uint4 a = src[0], b = src[1], c2 = src[2], d2 = src[3];
    uint4* dst = (uint4*)&xjb[jr*72 + half*32];
    dst[0]=a; dst[1]=b; dst[2]=c2; dst[3]=d2;
    if (tid < 128) sqs[tid] = sg[(tid>>5)*512 + (tid&31)];
  }

  unsigned kb[KK];
  #pragma unroll
  for (int t=0;t<KK;t++) kb[t] = 0xFFFFFFFFu;
  unsigned kbLast = 0xFFFFFFFFu;
  int cnt = 0;
  int q = w;
  int prow = lane;
  int rw = w*16;

  __syncthreads();

  bf16x8 A0 = *(const bf16x8*)&xrb[(rw + (lane & 15))*72 +      (lane>>4)*8];
  bf16x8 A1 = *(const bf16x8*)&xrb[(rw + (lane & 15))*72 + 32 + (lane>>4)*8];

  #pragma unroll 1
  for (int it = 0; it < 16; it++){
    uint4 pf0, pf1, pf2, pf3; float psq = 0.f;
    int itn = it + 1;
    int jr = tid >> 1, half = tid & 1;
    if (itn < 16){
      int jloc = (jr >> 5)*512 + itn*32 + (jr & 31);
      const uint4* src = (const uint4*)(xbg + (size_t)jloc*Hd + half*32);
      pf0 = src[0]; pf1 = src[1]; pf2 = src[2]; pf3 = src[3];
      if (tid < 128) psq = sg[(tid>>5)*512 + itn*32 + (tid&31)];
    }
    #pragma unroll
    for (int jb = 0; jb < 8; jb++){
      bf16x8 B0 = *(const bf16x8*)&xjb[(jb*16 + (lane & 15))*72 +      (lane>>4)*8];
      bf16x8 B1 = *(const bf16x8*)&xjb[(jb*16 + (lane & 15))*72 + 32 + (lane>>4)*8];
      f32x4 acc = {0.f, 0.f, 0.f, 0.f};
      acc = __builtin_amdgcn_mfma_f32_16x16x32_bf16(A0, B0, acc, 0, 0, 0);
      acc = __builtin_amdgcn_mfma_f32_16x16x32_bf16(A1, B1, acc, 0, 0, 0);
      int col = jb*16 + (lane & 15);
      float sqv = sqs[col];
      int rbase = rw + (lane>>4)*4;
      #pragma unroll
      for (int v=0; v<4; v++)
        Dt[(rbase + v)*133 + col] = fmaf(acc[v], -2.f, sqv);
    }
    __syncthreads();
    int jbase0 = q*512 + it*32;
    const float* drow = &Dt[prow*133 + q*32];
    #pragma unroll
    for (int i=0;i<32;i+=4){
      #pragma unroll
      for (int ii=0;ii<4;ii++){
        float s = drow[i+ii];
        unsigned u = __float_as_uint(s);
        u = ((int)u < 0) ? ~u : (u | 0x80000000u);
        unsigned key = (u & 0xFFFFF800u) | (unsigned)(jbase0 + i + ii);
        if (key < kbLast){ kc[cnt][tid] = key; cnt++; }
      }
      if (__any(cnt >= 4)){
        #pragma unroll 1
        for (int c=0;c<CAPB;c++){
          if (!__any(c < cnt)) break;
          unsigned k2 = (c < cnt) ? kc[c][tid] : 0xFFFFFFFFu;
          ins24(kb, k2);
        }
        cnt = 0; kbLast = kb[KK-1];
      }
    }
    if (itn < 16){
      uint4* dst = (uint4*)&xjb[jr*72 + half*32];
      dst[0]=pf0; dst[1]=pf1; dst[2]=pf2; dst[3]=pf3;
      if (tid < 128) sqs[tid] = psq;
    }
    __syncthreads();
  }
  #pragma unroll 1
  for (int c=0;c<CAPB;c++){
    if (!__any(c < cnt)) break;
    unsigned k2 = (c < cnt) ? kc[c][tid] : 0xFFFFFFFFu;
    ins24(kb, k2);
  }
  size_t base = (size_t)(g*Ng + r0 + prow)*96 + q*24;
  #pragma unroll
  for (int t=0;t<KK;t++)
    cand[base + t] = (unsigned short)(kb[t] & 2047u);
}

// ---------- exact rerank v3: 4-lane-cooperative coalesced gather + popcount ranking
__global__ __launch_bounds__(256) void rerank_kernel(const float* __restrict__ x,
        const unsigned short* __restrict__ cand, int* __restrict__ idx){
  __shared__ __align__(16) unsigned long long ks[4][96];
  int tid = threadIdx.x;
  int lane = tid & 63, w = tid >> 6;
  int row = blockIdx.x*4 + w;
  int g = row >> 11;
  const float* xg = x + (size_t)g*Ng*Hd;
  int chunk = lane & 3;        // 16B chunk within a row
  int cg = lane >> 2;          // candidate group 0..15
  // xrow chunks this lane needs: floats [16*it + 4*chunk .. +3]
  const float* xr = x + (size_t)row*Hd;
  float4 xc[4];
  #pragma unroll
  for (int it2=0; it2<4; it2++) xc[it2] = *(const float4*)(xr + 16*it2 + 4*chunk);

  #pragma unroll 1
  for (int pass=0; pass<6; pass++){
    int c = pass*16 + cg;
    int j = cand[(size_t)row*96 + c];
    const float* xj = xg + (size_t)j*Hd;
    float dot = 0.f, sqj = 0.f;
    #pragma unroll
    for (int it2=0; it2<4; it2++){
      float4 b = *(const float4*)(xj + 16*it2 + 4*chunk);
      float4 a = xc[it2];
      dot = fmaf(a.x, b.x, dot); dot = fmaf(a.y, b.y, dot);
      dot = fmaf(a.z, b.z, dot); dot = fmaf(a.w, b.w, dot);
      sqj = fmaf(b.x, b.x, sqj); sqj = fmaf(b.y, b.y, sqj);
      sqj = fmaf(b.z, b.z, sqj); sqj = fmaf(b.w, b.w, sqj);
    }
    dot += __shfl_xor(dot, 1, 64); dot += __shfl_xor(dot, 2, 64);
    sqj += __shfl_xor(sqj, 1, 64); sqj += __shfl_xor(sqj, 2, 64);
    if (chunk == 0){
      float dist = fmaf(dot, -2.f, sqj);   // row-constant +sq_i dropped (order-invariant)
      ks[w][c] = ((unsigned long long)enc_f32(dist) << 32) | (unsigned)j;
    }
  }
  __syncthreads();
  unsigned long long k0 = ks[w][lane];
  unsigned long long k1 = (lane < 32) ? ks[w][64 + lane] : ~0ULL;
  int r0 = 0, r1 = 0;
  #pragma unroll
  for (int c=0;c<96;c+=2){
    unsigned long long a = ks[w][c], b = ks[w][c+1];
    r0 += (a < k0) + (b < k0);
    r1 += (a < k1) + (b < k1);
  }
  if (r0 < Kn) idx[(size_t)row*Kn + r0] = g*Ng + (int)(k0 & 2047ULL);
  if (lane < 32 && r1 < Kn) idx[(size_t)row*Kn + r1] = g*Ng + (int)(k1 & 2047ULL);
}

// ---------- dynamic EdgeConv stage 2: edge-batched GEMM + node-max + atomicMax(enc)
__global__ __launch_bounds__(256,3) void emsg_kernel(
    const int* __restrict__ srcl,
    const float* __restrict__ P, const float* __restrict__ Q,
    const float* __restrict__ b1, const float* __restrict__ w2,
    unsigned int* __restrict__ enc){
  __shared__ __align__(16) char smem[49152];
  float* As = (float*)smem;
  float* Ws = (float*)(smem + 32768);
  float* p0 = (float*)smem;
  float* p1 = (float*)(smem + 64*33*4);
  int tid = threadIdx.x;
  int e0 = blockIdx.x * 256;
  int e = e0 + tid;
  int i = e / Kn;
  int j = srcl[e];
  const float* Pr = P + (size_t)i*Hd;
  const float* Qr = Q + (size_t)j*Hd;
  #pragma unroll
  for (int c=0;c<16;c++) Ws[c*256 + tid] = w2[c*256 + tid];

  int m0 = tid >> 3, n0 = tid & 7;
  float acc[8][8];
  #pragma unroll
  for (int a=0;a<8;a++)
    #pragma unroll
    for (int b=0;b<8;b++) acc[a][b]=0.f;

  #pragma unroll 1
  for (int kh=0; kh<2; kh++){
    __syncthreads();
    #pragma unroll
    for (int c=0;c<8;c++){
      int k = kh*32 + 4*c;
      float4 q4 = *(const float4*)(Qr + k);
      float4 pk = *(const float4*)(Pr + k);
      float4 b4 = *(const float4*)(b1 + k);
      As[(4*c+0)*256 + tid] = fmaxf(pk.x+q4.x+b4.x, 0.f);
      As[(4*c+1)*256 + tid] = fmaxf(pk.y+q4.y+b4.y, 0.f);
      As[(4*c+2)*256 + tid] = fmaxf(pk.z+q4.z+b4.z, 0.f);
      As[(4*c+3)*256 + tid] = fmaxf(pk.w+q4.w+b4.w, 0.f);
    }
    __syncthreads();
    #pragma unroll 4
    for (int kk=0; kk<32; kk++){
      int k = kh*32 + kk;
      float4 a0 = *(const float4*)&As[kk*256 + 8*m0];
      float4 a1 = *(const float4*)&As[kk*256 + 8*m0 + 4];
      float4 b0 = *(const float4*)&Ws[k*64 + 8*n0];
      float4 b1v = *(const float4*)&Ws[k*64 + 8*n0 + 4];
      FMA8(a0.x, 0) FMA8(a0.y, 1) FMA8(a0.z, 2) FMA8(a0.w, 3)
      FMA8(a1.x, 4) FMA8(a1.y, 5) FMA8(a1.z, 6) FMA8(a1.w, 7)
    }
  }
  int ebase = e0 + 8*m0;
  int nd0 = ebase / Kn;
  int split = (nd0+1)*Kn - ebase; if (split > 8) split = 8;
  float s0[8], s1[8];
  #pragma unroll
  for (int b=0;b<8;b++){ s0[b] = -INFINITY; s1[b] = -INFINITY; }
  #pragma unroll
  for (int a=0;a<8;a++)
    #pragma unroll
    for (int b=0;b<8;b++){
      if (a < split) s0[b] = fmaxf(s0[b], acc[a][b]);
      else           s1[b] = fmaxf(s1[b], acc[a][b]);
    }
  __syncthreads();
  #pragma unroll
  for (int b=0;b<8;b++){
    p0[(8*n0+b)*33 + m0] = s0[b];
    p1[(8*n0+b)*33 + m0] = s1[b];
  }
  __syncthreads();
  int nfirst = e0 / Kn;
  int ncnt = (e0 + 255) / Kn - nfirst + 1;
  int ch = tid & 63;
  for (int ln = tid >> 6; ln < ncnt; ln += 4){
    int nd = nfirst + ln;
    int glo = nd*Kn;      if (glo < e0)     glo = e0;
    int ghi = nd*Kn + Kn; if (ghi > e0+256) ghi = e0+256;
    int mlo = (glo - e0) >> 3, mhi = (ghi - 1 - e0) >> 3;
    float v = -INFINITY;
    for (int mm = mlo; mm <= mhi; mm++){
      int bn = (e0 + 8*mm) / Kn;
      if (bn == nd)     v = fmaxf(v, p0[ch*33 + mm]);
      if (bn + 1 == nd) v = fmaxf(v, p1[ch*33 + mm]);
    }
    atomicMax(&enc[(size_t)nd*Hd + ch], enc_f32(v));
  }
}

// ---------- final decode (no ELU): enc -> float + b2
__global__ __launch_bounds__(256) void decode_kernel(const unsigned int* __restrict__ enc,
         const float* __restrict__ b2, float* __restrict__ x){
  int t = blockIdx.x*256 + threadIdx.x;
  unsigned int e = enc[t];
  unsigned int bits = (e & 0x80000000u) ? (e ^ 0x80000000u) : ~e;
  float f = __uint_as_float(bits);
  if (isfinite(f)) f += b2[t & 63]; else f = 0.f;
  x[t] = f;
}

__global__ __launch_bounds__(64) void final_kernel(const float* __restrict__ h,
        const float* __restrict__ w, const float* __restrict__ bias,
        float* __restrict__ out){
  __shared__ float xs[Hd];
  int c = threadIdx.x;
  float wc[Hd];
  float bc = 0.f;
  if (c < Cd){
    #pragma unroll
    for (int d=0; d<Hd; d++) wc[d] = w[d*Cd + c];
    bc = bias[c];
  }
  for (int i = blockIdx.x; i < BNn; i += gridDim.x){
    __syncthreads();
    xs[c] = h[(size_t)i*Hd + c];
    __syncthreads();
    if (c < Cd){
      float s = bc;
      #pragma unroll
      for (int d=0; d<Hd; d++) s = fmaf(xs[d], wc[d], s);
      out[(size_t)i*Cd + c] = s;
    }
  }
}

extern "C" void kernel_launch(void* const* d_in, const int* in_sizes, int n_in,
                              void* d_out, int out_size, void* d_ws, size_t ws_size,
                              hipStream_t stream){
  const float* x0   = (const float*)d_in[0];
  const int*   ei   = (const int*)d_in[1];
  const float* c1w1 = (const float*)d_in[3];
  const float* c1b1 = (const float*)d_in[4];
  const float* c1w2 = (const float*)d_in[5];
  const float* c1b2 = (const float*)d_in[6];
  const float* d1w1 = (const float*)d_in[7];
  const float* d1b1 = (const float*)d_in[8];
  const float* d1w2 = (const float*)d_in[9];
  const float* d1b2 = (const float*)d_in[10];
  const float* d2w1 = (const float*)d_in[11];
  const float* d2b1 = (const float*)d_in[12];
  const float* d2w2 = (const float*)d_in[13];
  const float* d2b2 = (const float*)d_in[14];
  const float* linw = (const float*)d_in[15];
  const float* linb = (const float*)d_in[16];
  float* out = (float*)d_out;

  char* ws = (char*)d_ws;
  size_t off = 0;
  auto alloc = [&](size_t bytes)->char*{
    char* p = ws + off; off += (bytes + 255) & ~(size_t)255; return p;
  };
  float*        X    = (float*)alloc(sizeof(float)*(size_t)BNn*Hd);
  float*        P    = (float*)alloc(sizeof(float)*(size_t)BNn*Hd);
  float*        Q    = (float*)alloc(sizeof(float)*(size_t)BNn*Hd);
  float*        H2   = (float*)alloc(sizeof(float)*(size_t)BNn*Hd);  // aliases XB, ENID
  unsigned int* ENC  = (unsigned int*)alloc(sizeof(unsigned)*(size_t)BNn*Hd); // aliases CAND
  int*          SHRD = (int*)alloc(sizeof(int)*(size_t)En);   // CSRC, later IDX
  int*          DEG  = (int*)alloc(sizeof(int)*BNn);
  int*          RPTR = (int*)alloc(sizeof(int)*(BNn+1));
  int*          CUR  = (int*)alloc(sizeof(int)*BNn);
  float*        SQ   = (float*)alloc(sizeof(float)*BNn);
  float*        WPQ0 = (float*)alloc(sizeof(float)*3*128);
  float*        WPQ1 = (float*)alloc(sizeof(float)*64*128);
  float*        WPQ2 = (float*)alloc(sizeof(float)*64*128);
  int*            CSRC = SHRD;
  int*            IDX  = SHRD;
  int*            ENID = (int*)H2;
  unsigned short* XB   = (unsigned short*)H2;
  unsigned short* CAND = (unsigned short*)ENC;
  (void)ws_size; (void)in_sizes; (void)n_in; (void)out_size;

  // static EdgeConv: CSR sort + edge-batched GEMM + LDS-reduced max + fused decode
  prep_w_kernel<<<32, 256, 0, stream>>>(c1w1, d1w1, d2w1, WPQ0, WPQ1, WPQ2);
  zero_kernel<<<BNn/256, 256, 0, stream>>>(DEG);
  count_kernel<<<En/256, 256, 0, stream>>>(ei, DEG);
  gemm_pq_kernel<3><<<BNn/8, 128, 0, stream>>>(x0, WPQ0, P, Q);
  scan_kernel<<<1, 1024, 0, stream>>>(DEG, RPTR, CUR);
  scatter_kernel<<<En/256, 256, 0, stream>>>(ei, CUR, CSRC, ENID);
  init_enc_kernel<<<BNn*Hd/256, 256, 0, stream>>>(ENC);
  econv_gemm_kernel<<<En/256, 256, 0, stream>>>(CSRC, ENID, P, Q, c1b1, c1w2, ENC);
  decode_sqxb_kernel<<<BNn*Hd/256, 256, 0, stream>>>(ENC, c1b2, X, SQ, XB);

  // dynamic layer 1
  gemm_pq_kernel<64><<<BNn/8, 128, 0, stream>>>(X, WPQ1, P, Q);
  knn_kernel<<<Bg*32, 256, 0, stream>>>(XB, SQ, CAND);
  rerank_kernel<<<BNn/4, 256, 0, stream>>>(X, CAND, IDX);
  init_enc_kernel<<<BNn*Hd/256, 256, 0, stream>>>(ENC);
  emsg_kernel<<<En/256, 256, 0, stream>>>(IDX, P, Q, d1b1, d1w2, ENC);
  decode_sqxb_kernel<<<BNn*Hd/256, 256, 0, stream>>>(ENC, d1b2, X, SQ, XB);

  // dynamic layer 2
  gemm_pq_kernel<64><<<BNn/8, 128, 0, stream>>>(X, WPQ2, P, Q);
  knn_kernel<<<Bg*32, 256, 0, stream>>>(XB, SQ, CAND);
  rerank_kernel<<<BNn/4, 256, 0, stream>>>(X, CAND, IDX);
  init_enc_kernel<<<BNn*Hd/256, 256, 0, stream>>>(ENC);
  emsg_kernel<<<En/256, 256, 0, stream>>>(IDX, P, Q, d2b1, d2w2, ENC);
  decode_kernel<<<BNn*Hd/256, 256, 0, stream>>>(ENC, d2b2, H2);

  final_kernel<<<8192, 64, 0, stream>>>(H2, linw, linb, out);
}